// Round 1
// baseline (642.421 us; speedup 1.0000x reference)
//
#include <hip/hip_runtime.h>

// Problem constants: B=32, L=T=S=128, D=512, M = B*L = 4096.
#define DD 512
#define SS 128

// ---------------------------------------------------------------------------
// fp32 tiled GEMM: C[M,N] = A[M,K] @ W[K,N] (+ bias[N]) ; row-major all.
// 64x64 tile, 256 threads, 4x4 per thread, K-step 16, A-tile transposed in LDS.
// ---------------------------------------------------------------------------
__global__ __launch_bounds__(256)
void gemm_kernel(const float* __restrict__ A, const float* __restrict__ W,
                 const float* __restrict__ bias, float* __restrict__ C,
                 int M, int N, int K)
{
    __shared__ float As[16][64 + 4];   // As[k][m], pad 4 keeps float4 alignment, 2-way max conflict
    __shared__ float Bs[16][64 + 4];   // Bs[k][n]

    const int tid = threadIdx.x;
    const int tx = tid & 15;           // -> n
    const int ty = tid >> 4;           // -> m
    const int m0 = blockIdx.y * 64;
    const int n0 = blockIdx.x * 64;

    float acc[4][4] = {};

    for (int k0 = 0; k0 < K; k0 += 16) {
        #pragma unroll
        for (int j = 0; j < 4; ++j) {
            int idx = tid + j * 256;           // 0..1023
            int m = idx >> 4;                  // 0..63
            int k = idx & 15;                  // 0..15
            As[k][m] = A[(size_t)(m0 + m) * K + (k0 + k)];
        }
        #pragma unroll
        for (int j = 0; j < 4; ++j) {
            int idx = tid + j * 256;
            int k = idx >> 6;                  // 0..15
            int n = idx & 63;                  // 0..63
            Bs[k][n] = W[(size_t)(k0 + k) * N + (n0 + n)];
        }
        __syncthreads();
        #pragma unroll
        for (int k = 0; k < 16; ++k) {
            const float4 a4 = *(const float4*)&As[k][ty * 4];
            const float4 b4 = *(const float4*)&Bs[k][tx * 4];
            const float av[4] = {a4.x, a4.y, a4.z, a4.w};
            const float bv[4] = {b4.x, b4.y, b4.z, b4.w};
            #pragma unroll
            for (int i = 0; i < 4; ++i)
                #pragma unroll
                for (int j = 0; j < 4; ++j)
                    acc[i][j] = fmaf(av[i], bv[j], acc[i][j]);
        }
        __syncthreads();
    }

    #pragma unroll
    for (int i = 0; i < 4; ++i) {
        const int m = m0 + ty * 4 + i;
        #pragma unroll
        for (int j = 0; j < 4; ++j) {
            const int n = n0 + tx * 4 + j;
            float val = acc[i][j];
            if (bias) val += bias[n];
            C[(size_t)m * N + n] = val;
        }
    }
}

// ---------------------------------------------------------------------------
// Fused scores + softmax + context. One 256-thread block per (b,t).
//   score[s] = sum_d v[d]*tanh(wq[b,t,d] + uh[b,s,d])
//            = sumV - sum_d 2*v[d] / (exp2(C2*(wq+uh)) + 1)   (sumV drops: softmax shift-inv)
//   align = softmax_s(score);  c[b,t,d] = sum_s align[s]*mem[b,s,d]
// ---------------------------------------------------------------------------
__global__ __launch_bounds__(256)
void attn_kernel(const float* __restrict__ wq,   // [B,T,D]
                 const float* __restrict__ uh,   // [B,S,D]
                 const float* __restrict__ v,    // [D]
                 const float* __restrict__ mem,  // [B,S,D]
                 float* __restrict__ c_out,      // [B,T,D]
                 int T)
{
    const int b = blockIdx.y;
    const int t = blockIdx.x;
    const int tid = threadIdx.x;

    __shared__ float s_wq[DD];   // C2 * wq
    __shared__ float s_v2[DD];   // 2 * v
    __shared__ float s_sc[SS];
    __shared__ float s_e[SS];
    __shared__ float red[128];

    const float C2 = 2.8853900817779268f;       // 2*log2(e)
    const float L2E = 1.4426950408889634f;      // log2(e)

    const float* wqp = wq + ((size_t)b * T + t) * DD;
    for (int i = tid; i < DD; i += 256) {
        s_wq[i] = wqp[i] * C2;
        s_v2[i] = v[i] * 2.0f;
    }
    __syncthreads();

    // ---- scores: 2 threads per s, each sums 256 d's ----
    const int s    = tid >> 1;
    const int half = tid & 1;
    const float* up  = uh + ((size_t)b * SS + s) * DD + half * 256;
    const float* wq2 = s_wq + half * 256;
    const float* v2  = s_v2 + half * 256;
    float partial = 0.f;
    #pragma unroll 8
    for (int d = 0; d < 256; ++d) {
        float x = fmaf(C2, up[d], wq2[d]);              // C2*(wq+uh)
        float e = __builtin_amdgcn_exp2f(x);
        float r = __builtin_amdgcn_rcpf(e + 1.0f);
        partial = fmaf(v2[d], r, partial);
    }
    partial += __shfl_xor(partial, 1);
    if (half == 0) s_sc[s] = -partial;                  // score minus constant sumV
    __syncthreads();

    // ---- softmax over s (max-subtract, unnormalized exp, fold norm into c) ----
    if (tid < 128) red[tid] = s_sc[tid];
    __syncthreads();
    for (int st = 64; st > 0; st >>= 1) {
        if (tid < st) red[tid] = fmaxf(red[tid], red[tid + st]);
        __syncthreads();
    }
    const float mx = red[0];
    __syncthreads();
    if (tid < 128) {
        float e = __builtin_amdgcn_exp2f((s_sc[tid] - mx) * L2E);
        s_e[tid] = e;
        red[tid] = e;
    }
    __syncthreads();
    for (int st = 64; st > 0; st >>= 1) {
        if (tid < st) red[tid] += red[tid + st];
        __syncthreads();
    }
    const float rsum = __builtin_amdgcn_rcpf(red[0]);
    __syncthreads();

    // ---- context: 2 d's per thread, coalesced mem reads ----
    const float* mb = mem + (size_t)b * SS * DD;
    const int d0 = tid, d1 = tid + 256;
    float c0 = 0.f, c1 = 0.f;
    for (int si = 0; si < SS; ++si) {
        const float e = s_e[si];
        c0 = fmaf(e, mb[(size_t)si * DD + d0], c0);
        c1 = fmaf(e, mb[(size_t)si * DD + d1], c1);
    }
    float* cp = c_out + ((size_t)b * T + t) * DD;
    cp[d0] = c0 * rsum;
    cp[d1] = c1 * rsum;
}

// ---------------------------------------------------------------------------
// Mix + concat: Acat[i, 0:512] = (1-m)*c1 + m*c2 ; Acat[i, 512:1024] = (1-m)*no + m*cs
// ---------------------------------------------------------------------------
__global__ __launch_bounds__(256)
void mix_cat_kernel(const float* __restrict__ c1, const float* __restrict__ c2,
                    const float* __restrict__ s1, const float* __restrict__ s2,
                    const float* __restrict__ mix, float* __restrict__ Acat,
                    int M)
{
    const float m = mix[0];
    const float om = 1.0f - m;
    const int idx = blockIdx.x * 256 + threadIdx.x;     // over M*512
    const int row = idx >> 9;
    const int col = idx & 511;
    if (row < M) {
        const size_t p = (size_t)row * 512 + col;
        Acat[(size_t)row * 1024 + col]       = om * c1[p] + m * c2[p];
        Acat[(size_t)row * 1024 + 512 + col] = om * s1[p] + m * s2[p];
    }
}

// ---------------------------------------------------------------------------
extern "C" void kernel_launch(void* const* d_in, const int* in_sizes, int n_in,
                              void* d_out, int out_size, void* d_ws, size_t ws_size,
                              hipStream_t stream) {
    const float* cs   = (const float*)d_in[0]; // current_sotw [B,L,D]
    const float* no   = (const float*)d_in[1]; // new_obs      [B,L,D]
    const float* Wq   = (const float*)d_in[2]; // [D,D]
    const float* bq   = (const float*)d_in[3]; // [D]
    const float* Wc   = (const float*)d_in[4]; // [D,D]
    const float* v    = (const float*)d_in[5]; // [D]
    const float* Wout = (const float*)d_in[6]; // [2D,D]
    const float* bout = (const float*)d_in[7]; // [D]
    const float* mix  = (const float*)d_in[8]; // [1]
    float* out = (float*)d_out;

    const int B = 32, L = 128;
    const int M = B * L;                      // 4096
    const size_t BUF = (size_t)M * DD * sizeof(float);   // 8 MiB

    char* ws = (char*)d_ws;
    float* wq_buf = (float*)(ws);             // reused per direction
    float* uh_buf = (float*)(ws + BUF);
    float* c1_buf = (float*)(ws + 2 * BUF);
    float* c2_buf = (float*)(ws + 3 * BUF);
    float* Acat   = (float*)(ws);             // 16 MiB spanning first two bufs (wq/uh dead by then)

    dim3 bb(256);
    dim3 gg(DD / 64, M / 64);                 // (8, 64)
    dim3 ga(L, B);                            // (128, 32)

    // direction 1: source=new_obs, memory=current_sotw
    gemm_kernel<<<gg, bb, 0, stream>>>(no, Wq, bq,      wq_buf, M, DD, DD);
    gemm_kernel<<<gg, bb, 0, stream>>>(cs, Wc, nullptr, uh_buf, M, DD, DD);
    attn_kernel<<<ga, bb, 0, stream>>>(wq_buf, uh_buf, v, cs, c1_buf, L);

    // direction 2: source=current_sotw, memory=new_obs
    gemm_kernel<<<gg, bb, 0, stream>>>(cs, Wq, bq,      wq_buf, M, DD, DD);
    gemm_kernel<<<gg, bb, 0, stream>>>(no, Wc, nullptr, uh_buf, M, DD, DD);
    attn_kernel<<<ga, bb, 0, stream>>>(wq_buf, uh_buf, v, no, c2_buf, L);

    // mix + concat, then final GEMM (K=1024) with bias
    mix_cat_kernel<<<dim3((M * 512) / 256), bb, 0, stream>>>(c1_buf, c2_buf, no, cs, mix, Acat, M);
    gemm_kernel<<<gg, bb, 0, stream>>>(Acat, Wout, bout, out, M, DD, 1024);
}

// Round 2
// 468.672 us; speedup vs baseline: 1.3707x; 1.3707x over previous
//
#include <hip/hip_runtime.h>

// Problem constants: B=32, L=T=S=128, D=512, M = B*L = 4096.
#define DD 512
#define SS 128
#define TT 16          // t-rows per attn block
#define SCH 32         // s-chunk rows staged in LDS
#define STR 516        // LDS row stride in floats: 16B-aligned, rows offset 4 banks -> worst 2-way (free)

// ---------------------------------------------------------------------------
// fp32 tiled GEMM: C[M,N] = A[M,K] @ W[K,N] (+ bias[N]) ; row-major all.
// ---------------------------------------------------------------------------
__global__ __launch_bounds__(256)
void gemm_kernel(const float* __restrict__ A, const float* __restrict__ W,
                 const float* __restrict__ bias, float* __restrict__ C,
                 int M, int N, int K)
{
    __shared__ float As[16][64 + 4];
    __shared__ float Bs[16][64 + 4];

    const int tid = threadIdx.x;
    const int tx = tid & 15;
    const int ty = tid >> 4;
    const int m0 = blockIdx.y * 64;
    const int n0 = blockIdx.x * 64;

    float acc[4][4] = {};

    for (int k0 = 0; k0 < K; k0 += 16) {
        #pragma unroll
        for (int j = 0; j < 4; ++j) {
            int idx = tid + j * 256;
            int m = idx >> 4;
            int k = idx & 15;
            As[k][m] = A[(size_t)(m0 + m) * K + (k0 + k)];
        }
        #pragma unroll
        for (int j = 0; j < 4; ++j) {
            int idx = tid + j * 256;
            int k = idx >> 6;
            int n = idx & 63;
            Bs[k][n] = W[(size_t)(k0 + k) * N + (n0 + n)];
        }
        __syncthreads();
        #pragma unroll
        for (int k = 0; k < 16; ++k) {
            const float4 a4 = *(const float4*)&As[k][ty * 4];
            const float4 b4 = *(const float4*)&Bs[k][tx * 4];
            const float av[4] = {a4.x, a4.y, a4.z, a4.w};
            const float bv[4] = {b4.x, b4.y, b4.z, b4.w};
            #pragma unroll
            for (int i = 0; i < 4; ++i)
                #pragma unroll
                for (int j = 0; j < 4; ++j)
                    acc[i][j] = fmaf(av[i], bv[j], acc[i][j]);
        }
        __syncthreads();
    }

    #pragma unroll
    for (int i = 0; i < 4; ++i) {
        const int m = m0 + ty * 4 + i;
        #pragma unroll
        for (int j = 0; j < 4; ++j) {
            const int n = n0 + tx * 4 + j;
            float val = acc[i][j];
            if (bias) val += bias[n];
            C[(size_t)m * N + n] = val;
        }
    }
}

// ---------------------------------------------------------------------------
// Fused scores + softmax + context, tiled.
// Block = (b, 16 t-rows), 512 threads. All global loads coalesced float4.
//   score[t,s] = -sum_d 2*v[d] / (exp2(C2*(wq[t,d]+uh[s,d])) + 1)   (softmax shift-inv)
// Phase A: stage wq tile (pre-scaled) + uh s-chunks in LDS; 1 thread per (t,s).
// Softmax: per-row shfl reduce, normalized weights written back to LDS.
// Phase B: c[t,d] = sum_s e[t,s]*mem[s,d]; wave = 4 t-rows x 256 d's, float4.
// ---------------------------------------------------------------------------
__global__ __launch_bounds__(512)
void attn_fused(const float* __restrict__ wq,   // [B,T,D]
                const float* __restrict__ uh,   // [B,S,D]
                const float* __restrict__ v,    // [D]
                const float* __restrict__ mem,  // [B,S,D]
                float* __restrict__ c_out)      // [B,T,D]
{
    __shared__ float s_wq[TT * STR];    // C2 * wq tile
    __shared__ float s_uh[SCH * STR];   // uh chunk
    __shared__ float s_v2[DD];          // 2 * v
    __shared__ float s_sc[TT * SS];     // scores -> normalized weights

    const int b  = blockIdx.y;
    const int t0 = blockIdx.x * TT;
    const int tid = threadIdx.x;

    const float C2  = 2.8853900817779268f;   // 2*log2(e)
    const float L2E = 1.4426950408889634f;

    // ---- stage wq tile (scaled by C2) and v2 ----
    {
        const float4* wp = (const float4*)(wq + ((size_t)b * SS + t0) * DD);
        for (int i = tid; i < TT * (DD / 4); i += 512) {
            const int row = i >> 7;          // / (DD/4)
            const int c4  = i & 127;
            float4 val = wp[row * 128 + c4];
            val.x *= C2; val.y *= C2; val.z *= C2; val.w *= C2;
            *(float4*)&s_wq[row * STR + c4 * 4] = val;
        }
        for (int i = tid; i < DD; i += 512) s_v2[i] = v[i] * 2.0f;
    }

    // ---- phase A: scores ----
    const int t  = tid & 15;       // wave lanes: 16 t x 4 s -> uh conflict-free, wq 2-way
    const int sl = tid >> 4;       // 0..31
    const float* wqr = &s_wq[t * STR];
    const float* uhr = &s_uh[sl * STR];

    for (int sc0 = 0; sc0 < SS; sc0 += SCH) {
        __syncthreads();   // previous chunk fully consumed (and wq staged, 1st iter)
        const float4* up = (const float4*)(uh + ((size_t)b * SS + sc0) * DD);
        for (int i = tid; i < SCH * (DD / 4); i += 512) {
            const int row = i >> 7;
            const int c4  = i & 127;
            *(float4*)&s_uh[row * STR + c4 * 4] = up[row * 128 + c4];
        }
        __syncthreads();

        float a0 = 0.f, a1 = 0.f, a2 = 0.f, a3 = 0.f;
        #pragma unroll 4
        for (int d = 0; d < DD; d += 4) {
            const float4 w4 = *(const float4*)&wqr[d];
            const float4 u4 = *(const float4*)&uhr[d];
            const float4 v4 = *(const float4*)&s_v2[d];
            a0 = fmaf(v4.x, __builtin_amdgcn_rcpf(__builtin_amdgcn_exp2f(fmaf(C2, u4.x, w4.x)) + 1.f), a0);
            a1 = fmaf(v4.y, __builtin_amdgcn_rcpf(__builtin_amdgcn_exp2f(fmaf(C2, u4.y, w4.y)) + 1.f), a1);
            a2 = fmaf(v4.z, __builtin_amdgcn_rcpf(__builtin_amdgcn_exp2f(fmaf(C2, u4.z, w4.z)) + 1.f), a2);
            a3 = fmaf(v4.w, __builtin_amdgcn_rcpf(__builtin_amdgcn_exp2f(fmaf(C2, u4.w, w4.w)) + 1.f), a3);
        }
        s_sc[t * SS + sc0 + sl] = -((a0 + a1) + (a2 + a3));
    }
    __syncthreads();

    // ---- softmax per t-row (16 rows x 128 s); write back normalized weights ----
    {
        const int tr  = tid >> 5;        // 0..15
        const int l32 = tid & 31;
        float x0 = s_sc[tr * SS + l32];
        float x1 = s_sc[tr * SS + l32 + 32];
        float x2 = s_sc[tr * SS + l32 + 64];
        float x3 = s_sc[tr * SS + l32 + 96];
        float mx = fmaxf(fmaxf(x0, x1), fmaxf(x2, x3));
        #pragma unroll
        for (int off = 16; off > 0; off >>= 1) mx = fmaxf(mx, __shfl_xor(mx, off));
        const float e0 = __builtin_amdgcn_exp2f((x0 - mx) * L2E);
        const float e1 = __builtin_amdgcn_exp2f((x1 - mx) * L2E);
        const float e2 = __builtin_amdgcn_exp2f((x2 - mx) * L2E);
        const float e3 = __builtin_amdgcn_exp2f((x3 - mx) * L2E);
        float sum = (e0 + e1) + (e2 + e3);
        #pragma unroll
        for (int off = 16; off > 0; off >>= 1) sum += __shfl_xor(sum, off);
        const float rs = __builtin_amdgcn_rcpf(sum);
        __syncthreads();   // everyone done reading raw scores before overwrite
        s_sc[tr * SS + l32]      = e0 * rs;
        s_sc[tr * SS + l32 + 32] = e1 * rs;
        s_sc[tr * SS + l32 + 64] = e2 * rs;
        s_sc[tr * SS + l32 + 96] = e3 * rs;
    }
    __syncthreads();

    // ---- phase B: context. wave w -> 4 t-rows, 256 d's (half) ----
    {
        const int w    = tid >> 6;           // 0..7
        const int lane = tid & 63;
        const int tg   = w >> 1;             // 0..3 -> t rows tg*4..tg*4+3
        const int half = w & 1;
        const int d    = half * 256 + lane * 4;
        const float* mb = mem + (size_t)b * SS * DD;

        float4 ac0 = {0,0,0,0}, ac1 = {0,0,0,0}, ac2 = {0,0,0,0}, ac3 = {0,0,0,0};
        for (int s = 0; s < SS; ++s) {
            const float4 mv = *(const float4*)&mb[(size_t)s * DD + d];
            const float e0 = s_sc[(tg * 4 + 0) * SS + s];
            const float e1 = s_sc[(tg * 4 + 1) * SS + s];
            const float e2 = s_sc[(tg * 4 + 2) * SS + s];
            const float e3 = s_sc[(tg * 4 + 3) * SS + s];
            ac0.x = fmaf(e0, mv.x, ac0.x); ac0.y = fmaf(e0, mv.y, ac0.y);
            ac0.z = fmaf(e0, mv.z, ac0.z); ac0.w = fmaf(e0, mv.w, ac0.w);
            ac1.x = fmaf(e1, mv.x, ac1.x); ac1.y = fmaf(e1, mv.y, ac1.y);
            ac1.z = fmaf(e1, mv.z, ac1.z); ac1.w = fmaf(e1, mv.w, ac1.w);
            ac2.x = fmaf(e2, mv.x, ac2.x); ac2.y = fmaf(e2, mv.y, ac2.y);
            ac2.z = fmaf(e2, mv.z, ac2.z); ac2.w = fmaf(e2, mv.w, ac2.w);
            ac3.x = fmaf(e3, mv.x, ac3.x); ac3.y = fmaf(e3, mv.y, ac3.y);
            ac3.z = fmaf(e3, mv.z, ac3.z); ac3.w = fmaf(e3, mv.w, ac3.w);
        }
        float* cp = c_out + ((size_t)b * SS + t0 + tg * 4) * DD + d;
        *(float4*)&cp[0 * DD] = ac0;
        *(float4*)&cp[1 * DD] = ac1;
        *(float4*)&cp[2 * DD] = ac2;
        *(float4*)&cp[3 * DD] = ac3;
    }
}

// ---------------------------------------------------------------------------
// Mix + concat: Acat[i,0:512] = (1-m)*c1 + m*c2 ; Acat[i,512:1024] = (1-m)*s1 + m*s2
// ---------------------------------------------------------------------------
__global__ __launch_bounds__(256)
void mix_cat_kernel(const float* __restrict__ c1, const float* __restrict__ c2,
                    const float* __restrict__ s1, const float* __restrict__ s2,
                    const float* __restrict__ mix, float* __restrict__ Acat,
                    int M)
{
    const float m = mix[0];
    const float om = 1.0f - m;
    const int idx = blockIdx.x * 256 + threadIdx.x;
    const int row = idx >> 9;
    const int col = idx & 511;
    if (row < M) {
        const size_t p = (size_t)row * 512 + col;
        Acat[(size_t)row * 1024 + col]       = om * c1[p] + m * c2[p];
        Acat[(size_t)row * 1024 + 512 + col] = om * s1[p] + m * s2[p];
    }
}

// ---------------------------------------------------------------------------
extern "C" void kernel_launch(void* const* d_in, const int* in_sizes, int n_in,
                              void* d_out, int out_size, void* d_ws, size_t ws_size,
                              hipStream_t stream) {
    const float* cs   = (const float*)d_in[0];
    const float* no   = (const float*)d_in[1];
    const float* Wq   = (const float*)d_in[2];
    const float* bq   = (const float*)d_in[3];
    const float* Wc   = (const float*)d_in[4];
    const float* v    = (const float*)d_in[5];
    const float* Wout = (const float*)d_in[6];
    const float* bout = (const float*)d_in[7];
    const float* mix  = (const float*)d_in[8];
    float* out = (float*)d_out;

    const int B = 32, L = 128;
    const int M = B * L;                                 // 4096
    const size_t BUF = (size_t)M * DD * sizeof(float);   // 8 MiB

    char* ws = (char*)d_ws;
    float* wq_buf = (float*)(ws);
    float* uh_buf = (float*)(ws + BUF);
    float* c1_buf = (float*)(ws + 2 * BUF);
    float* c2_buf = (float*)(ws + 3 * BUF);
    float* Acat   = (float*)(ws);                        // spans first two bufs (dead by then)

    dim3 bb(256);
    dim3 gg(DD / 64, M / 64);                            // (8, 64)
    dim3 ga(L / TT, B);                                  // (8, 32)

    // direction 1: source=new_obs, memory=current_sotw
    gemm_kernel<<<gg, bb, 0, stream>>>(no, Wq, bq,      wq_buf, M, DD, DD);
    gemm_kernel<<<gg, bb, 0, stream>>>(cs, Wc, nullptr, uh_buf, M, DD, DD);
    attn_fused<<<ga, dim3(512), 0, stream>>>(wq_buf, uh_buf, v, cs, c1_buf);

    // direction 2: source=current_sotw, memory=new_obs
    gemm_kernel<<<gg, bb, 0, stream>>>(cs, Wq, bq,      wq_buf, M, DD, DD);
    gemm_kernel<<<gg, bb, 0, stream>>>(no, Wc, nullptr, uh_buf, M, DD, DD);
    attn_fused<<<ga, dim3(512), 0, stream>>>(wq_buf, uh_buf, v, no, c2_buf);

    // mix + concat, then final GEMM (K=1024) with bias
    mix_cat_kernel<<<dim3((M * 512) / 256), bb, 0, stream>>>(c1_buf, c2_buf, no, cs, mix, Acat, M);
    gemm_kernel<<<gg, bb, 0, stream>>>(Acat, Wout, bout, out, M, DD, 1024);
}

// Round 4
// 317.635 us; speedup vs baseline: 2.0225x; 1.4755x over previous
//
#include <hip/hip_runtime.h>

// B=32, L=T=S=128, D=512, M = B*L = 4096.
#define DD 512
#define SS 128
#define TT 16          // t-rows per attn block
#define SCH 16         // s-chunk rows staged in LDS
#define C2F 2.8853900817779268f   // 2*log2(e)
#define L2EF 1.4426950408889634f

typedef __bf16 bf16x8 __attribute__((ext_vector_type(8)));
typedef float f32x4 __attribute__((ext_vector_type(4)));
typedef unsigned int uint32x4 __attribute__((ext_vector_type(4)));

__device__ __forceinline__ unsigned short f2bf(float f) {
    unsigned int u = __builtin_bit_cast(unsigned int, f);
    u += 0x7fffu + ((u >> 16) & 1u);            // RTNE
    return (unsigned short)(u >> 16);
}
__device__ __forceinline__ float bflo(unsigned int u) { return __builtin_bit_cast(float, u << 16); }
__device__ __forceinline__ float bfhi(unsigned int u) { return __builtin_bit_cast(float, u & 0xffff0000u); }

// ---------------------------------------------------------------------------
// f32 -> bf16 elementwise (n8 = n/8 vector groups)
// ---------------------------------------------------------------------------
__global__ __launch_bounds__(256)
void f32_to_bf16_k(const float* __restrict__ in, unsigned short* __restrict__ out, int n8)
{
    int i = blockIdx.x * 256 + threadIdx.x;
    if (i < n8) {
        const float4 a = ((const float4*)in)[2 * i];
        const float4 b = ((const float4*)in)[2 * i + 1];
        uint32x4 o;
        o[0] = (unsigned)f2bf(a.x) | ((unsigned)f2bf(a.y) << 16);
        o[1] = (unsigned)f2bf(a.z) | ((unsigned)f2bf(a.w) << 16);
        o[2] = (unsigned)f2bf(b.x) | ((unsigned)f2bf(b.y) << 16);
        o[3] = (unsigned)f2bf(b.z) | ((unsigned)f2bf(b.w) << 16);
        ((uint32x4*)out)[i] = o;
    }
}

// ---------------------------------------------------------------------------
// Transpose + convert: out[c][r] = bf16(in[r][c]); R,C multiples of 64.
// ---------------------------------------------------------------------------
__global__ __launch_bounds__(256)
void transpose_bf16(const float* __restrict__ in, unsigned short* __restrict__ out, int R, int C)
{
    __shared__ float t[64][65];
    const int r0 = blockIdx.y * 64, c0 = blockIdx.x * 64;
    const int tid = threadIdx.x;
    const int lc = tid & 63, lr = tid >> 6;
    #pragma unroll
    for (int i = 0; i < 16; ++i) {
        int r = lr + i * 4;
        t[r][lc] = in[(size_t)(r0 + r) * C + c0 + lc];
    }
    __syncthreads();
    #pragma unroll
    for (int i = 0; i < 16; ++i) {
        int rr = lr + i * 4;     // column of input = row of output
        out[(size_t)(c0 + rr) * R + r0 + lc] = f2bf(t[lc][rr]);
    }
}

// ---------------------------------------------------------------------------
// bf16 MFMA GEMM: C[M,N] = A[M,K](bf16) @ Bt[N,K](bf16)^T (+bias), optional *C2.
// 128x64 tile, BK=64, 256 thr (4 waves 2x2), reg-prefetch of next K-tile.
// mfma_f32_16x16x32_bf16: A lane: row=lane&15, k=(lane>>4)*8+i ; B: col=lane&15;
// C/D: col=lane&15, row=(lane>>4)*4+reg  [m89-verified]
// ---------------------------------------------------------------------------
template<int K, bool OUT_BF16, bool SCALE>
__global__ __launch_bounds__(256)
void gemm_mfma(const unsigned short* __restrict__ A, const unsigned short* __restrict__ Bt,
               const float* __restrict__ bias, void* __restrict__ Cout, int N)
{
    constexpr int BM = 128, BN = 64, BK = 64, LDA = BK + 8;
    __shared__ __align__(16) unsigned short As[BM][LDA];
    __shared__ __align__(16) unsigned short Bs[BN][LDA];

    const int tid = threadIdx.x;
    const int m0 = blockIdx.y * BM, n0 = blockIdx.x * BN;
    const int lane = tid & 63, wid = tid >> 6;
    const int wr = wid >> 1, wc = wid & 1;
    const int lr = lane & 15, kb = lane >> 4;

    f32x4 acc[4][2] = {};
    uint32x4 ra[4], rb[2];

    auto LOADK = [&](int k0) {
        #pragma unroll
        for (int j = 0; j < 4; ++j) {
            int id = tid + 256 * j; int r = id >> 3, s = id & 7;
            ra[j] = *(const uint32x4*)&A[(size_t)(m0 + r) * K + k0 + s * 8];
        }
        #pragma unroll
        for (int j = 0; j < 2; ++j) {
            int id = tid + 256 * j; int r = id >> 3, s = id & 7;
            rb[j] = *(const uint32x4*)&Bt[(size_t)(n0 + r) * K + k0 + s * 8];
        }
    };

    LOADK(0);
    #pragma unroll 1
    for (int step = 0; step < K / BK; ++step) {
        __syncthreads();
        #pragma unroll
        for (int j = 0; j < 4; ++j) {
            int id = tid + 256 * j; int r = id >> 3, s = id & 7;
            *(uint32x4*)&As[r][s * 8] = ra[j];
        }
        #pragma unroll
        for (int j = 0; j < 2; ++j) {
            int id = tid + 256 * j; int r = id >> 3, s = id & 7;
            *(uint32x4*)&Bs[r][s * 8] = rb[j];
        }
        __syncthreads();
        if (step + 1 < K / BK) LOADK((step + 1) * BK);
        #pragma unroll
        for (int kk = 0; kk < BK; kk += 32) {
            bf16x8 b0 = __builtin_bit_cast(bf16x8, *(const uint32x4*)&Bs[wc * 32 + lr][kk + kb * 8]);
            bf16x8 b1 = __builtin_bit_cast(bf16x8, *(const uint32x4*)&Bs[wc * 32 + 16 + lr][kk + kb * 8]);
            #pragma unroll
            for (int mf = 0; mf < 4; ++mf) {
                bf16x8 a0 = __builtin_bit_cast(bf16x8, *(const uint32x4*)&As[wr * 64 + mf * 16 + lr][kk + kb * 8]);
                acc[mf][0] = __builtin_amdgcn_mfma_f32_16x16x32_bf16(a0, b0, acc[mf][0], 0, 0, 0);
                acc[mf][1] = __builtin_amdgcn_mfma_f32_16x16x32_bf16(a0, b1, acc[mf][1], 0, 0, 0);
            }
        }
    }

    #pragma unroll
    for (int nf = 0; nf < 2; ++nf) {
        const int col = n0 + wc * 32 + nf * 16 + lr;
        const float bv = bias ? bias[col] : 0.0f;
        #pragma unroll
        for (int mf = 0; mf < 4; ++mf) {
            const int row = m0 + wr * 64 + mf * 16 + kb * 4;
            #pragma unroll
            for (int r = 0; r < 4; ++r) {
                float valf = acc[mf][nf][r] + bv;
                if (SCALE) valf *= C2F;
                if (OUT_BF16) ((unsigned short*)Cout)[(size_t)(row + r) * N + col] = f2bf(valf);
                else          ((float*)Cout)[(size_t)(row + r) * N + col] = valf;
            }
        }
    }
}

// ---------------------------------------------------------------------------
// Fused scores + softmax + context. wq (bf16, pre-scaled by 2*log2e incl bias),
// uh (bf16). score[t,s] = -sum_d 2*v[d]/(exp2(wq_s + C2*uh) + 1)  (shift-inv)
// Block = (b, 16 t-rows), 512 thr, 43.5KB LDS -> 3 blocks/CU.
// ---------------------------------------------------------------------------
__global__ __launch_bounds__(512, 6)
void attn_fused(const unsigned short* __restrict__ wq,  // [B,T,D] bf16 *C2
                const unsigned short* __restrict__ uh,  // [B,S,D] bf16
                const float* __restrict__ v,            // [D]
                const float* __restrict__ mem,          // [B,S,D] f32
                unsigned short* __restrict__ c_out)     // [B,T,D] bf16
{
    __shared__ __align__(16) unsigned short s_wq[TT][DD + 8];
    __shared__ __align__(16) unsigned short s_uh[SCH][DD + 8];
    __shared__ float s_v2[DD];
    __shared__ float s_sc[TT * SS];

    const int b = blockIdx.y;
    const int t0 = blockIdx.x * TT;
    const int tid = threadIdx.x;

    // ---- stage wq tile + v2 ----
    {
        const uint32x4* wp = (const uint32x4*)(wq + ((size_t)b * SS + t0) * DD);
        for (int i = tid; i < TT * 64; i += 512) {
            int row = i >> 6, c8 = i & 63;
            *(uint32x4*)&s_wq[row][c8 * 8] = wp[row * 64 + c8];
        }
        for (int i = tid; i < DD; i += 512) s_v2[i] = v[i] * 2.0f;
    }

    // ---- phase A: scores. thread -> (t, s-in-chunk, half) ----
    const int t  = (tid >> 1) & 15;
    const int sr = (tid >> 5) & 15;
    const int hh = tid & 1;

    for (int sc0 = 0; sc0 < SS; sc0 += SCH) {
        __syncthreads();
        const uint32x4* up = (const uint32x4*)(uh + ((size_t)b * SS + sc0) * DD);
        for (int i = tid; i < SCH * 64; i += 512) {
            int row = i >> 6, c8 = i & 63;
            *(uint32x4*)&s_uh[row][c8 * 8] = up[row * 64 + c8];
        }
        __syncthreads();

        const unsigned int* wrow = (const unsigned int*)&s_wq[t][hh * 256];
        const unsigned int* urow = (const unsigned int*)&s_uh[sr][hh * 256];
        const float* v2 = &s_v2[hh * 256];

        float a0 = 0.f, a1 = 0.f, a2 = 0.f, a3 = 0.f;
        #pragma unroll 2
        for (int j = 0; j < 128; j += 4) {          // 8 bf16 elems per iter
            uint32x4 w4 = *(const uint32x4*)&wrow[j];
            uint32x4 u4 = *(const uint32x4*)&urow[j];
            const float4 vA = *(const float4*)&v2[2 * j];
            const float4 vB = *(const float4*)&v2[2 * j + 4];
            float x, e;
            x = fmaf(C2F, bflo(u4[0]), bflo(w4[0])); e = __builtin_amdgcn_exp2f(x);
            a0 = fmaf(vA.x, __builtin_amdgcn_rcpf(e + 1.f), a0);
            x = fmaf(C2F, bfhi(u4[0]), bfhi(w4[0])); e = __builtin_amdgcn_exp2f(x);
            a1 = fmaf(vA.y, __builtin_amdgcn_rcpf(e + 1.f), a1);
            x = fmaf(C2F, bflo(u4[1]), bflo(w4[1])); e = __builtin_amdgcn_exp2f(x);
            a2 = fmaf(vA.z, __builtin_amdgcn_rcpf(e + 1.f), a2);
            x = fmaf(C2F, bfhi(u4[1]), bfhi(w4[1])); e = __builtin_amdgcn_exp2f(x);
            a3 = fmaf(vA.w, __builtin_amdgcn_rcpf(e + 1.f), a3);
            x = fmaf(C2F, bflo(u4[2]), bflo(w4[2])); e = __builtin_amdgcn_exp2f(x);
            a0 = fmaf(vB.x, __builtin_amdgcn_rcpf(e + 1.f), a0);
            x = fmaf(C2F, bfhi(u4[2]), bfhi(w4[2])); e = __builtin_amdgcn_exp2f(x);
            a1 = fmaf(vB.y, __builtin_amdgcn_rcpf(e + 1.f), a1);
            x = fmaf(C2F, bflo(u4[3]), bflo(w4[3])); e = __builtin_amdgcn_exp2f(x);
            a2 = fmaf(vB.z, __builtin_amdgcn_rcpf(e + 1.f), a2);
            x = fmaf(C2F, bfhi(u4[3]), bfhi(w4[3])); e = __builtin_amdgcn_exp2f(x);
            a3 = fmaf(vB.w, __builtin_amdgcn_rcpf(e + 1.f), a3);
        }
        float partial = (a0 + a1) + (a2 + a3);
        partial += __shfl_xor(partial, 1);
        if (hh == 0) s_sc[t * SS + sc0 + sr] = -partial;
    }
    __syncthreads();

    // ---- softmax per t-row; write back normalized weights ----
    {
        const int tr  = tid >> 5;
        const int l32 = tid & 31;
        float x0 = s_sc[tr * SS + l32];
        float x1 = s_sc[tr * SS + l32 + 32];
        float x2 = s_sc[tr * SS + l32 + 64];
        float x3 = s_sc[tr * SS + l32 + 96];
        float mx = fmaxf(fmaxf(x0, x1), fmaxf(x2, x3));
        #pragma unroll
        for (int off = 16; off > 0; off >>= 1) mx = fmaxf(mx, __shfl_xor(mx, off));
        const float e0 = __builtin_amdgcn_exp2f((x0 - mx) * L2EF);
        const float e1 = __builtin_amdgcn_exp2f((x1 - mx) * L2EF);
        const float e2 = __builtin_amdgcn_exp2f((x2 - mx) * L2EF);
        const float e3 = __builtin_amdgcn_exp2f((x3 - mx) * L2EF);
        float sum = (e0 + e1) + (e2 + e3);
        #pragma unroll
        for (int off = 16; off > 0; off >>= 1) sum += __shfl_xor(sum, off);
        const float rs = __builtin_amdgcn_rcpf(sum);
        __syncthreads();
        s_sc[tr * SS + l32]      = e0 * rs;
        s_sc[tr * SS + l32 + 32] = e1 * rs;
        s_sc[tr * SS + l32 + 64] = e2 * rs;
        s_sc[tr * SS + l32 + 96] = e3 * rs;
    }
    __syncthreads();

    // ---- phase B: context; wave -> 4 t-rows x 256 d's; bf16 out ----
    {
        const int w    = tid >> 6;
        const int lane = tid & 63;
        const int tg   = w >> 1;
        const int hf   = w & 1;
        const int d    = hf * 256 + lane * 4;
        const float* mb = mem + (size_t)b * SS * DD;

        float4 ac0 = {0,0,0,0}, ac1 = {0,0,0,0}, ac2 = {0,0,0,0}, ac3 = {0,0,0,0};
        for (int s = 0; s < SS; ++s) {
            const float4 mv = *(const float4*)&mb[(size_t)s * DD + d];
            const float e0 = s_sc[(tg * 4 + 0) * SS + s];
            const float e1 = s_sc[(tg * 4 + 1) * SS + s];
            const float e2 = s_sc[(tg * 4 + 2) * SS + s];
            const float e3 = s_sc[(tg * 4 + 3) * SS + s];
            ac0.x = fmaf(e0, mv.x, ac0.x); ac0.y = fmaf(e0, mv.y, ac0.y);
            ac0.z = fmaf(e0, mv.z, ac0.z); ac0.w = fmaf(e0, mv.w, ac0.w);
            ac1.x = fmaf(e1, mv.x, ac1.x); ac1.y = fmaf(e1, mv.y, ac1.y);
            ac1.z = fmaf(e1, mv.z, ac1.z); ac1.w = fmaf(e1, mv.w, ac1.w);
            ac2.x = fmaf(e2, mv.x, ac2.x); ac2.y = fmaf(e2, mv.y, ac2.y);
            ac2.z = fmaf(e2, mv.z, ac2.z); ac2.w = fmaf(e2, mv.w, ac2.w);
            ac3.x = fmaf(e3, mv.x, ac3.x); ac3.y = fmaf(e3, mv.y, ac3.y);
            ac3.z = fmaf(e3, mv.z, ac3.z); ac3.w = fmaf(e3, mv.w, ac3.w);
        }
        unsigned short* cp = c_out + ((size_t)b * SS + t0 + tg * 4) * DD + d;
        uint2 st;
        st.x = (unsigned)f2bf(ac0.x) | ((unsigned)f2bf(ac0.y) << 16);
        st.y = (unsigned)f2bf(ac0.z) | ((unsigned)f2bf(ac0.w) << 16);
        *(uint2*)&cp[0 * DD] = st;
        st.x = (unsigned)f2bf(ac1.x) | ((unsigned)f2bf(ac1.y) << 16);
        st.y = (unsigned)f2bf(ac1.z) | ((unsigned)f2bf(ac1.w) << 16);
        *(uint2*)&cp[1 * DD] = st;
        st.x = (unsigned)f2bf(ac2.x) | ((unsigned)f2bf(ac2.y) << 16);
        st.y = (unsigned)f2bf(ac2.z) | ((unsigned)f2bf(ac2.w) << 16);
        *(uint2*)&cp[2 * DD] = st;
        st.x = (unsigned)f2bf(ac3.x) | ((unsigned)f2bf(ac3.y) << 16);
        st.y = (unsigned)f2bf(ac3.z) | ((unsigned)f2bf(ac3.w) << 16);
        *(uint2*)&cp[3 * DD] = st;
    }
}

// ---------------------------------------------------------------------------
// Mix + concat -> Acat bf16 [M][1024]
// ---------------------------------------------------------------------------
__global__ __launch_bounds__(256)
void mix_cat(const unsigned short* __restrict__ c1, const unsigned short* __restrict__ c2,
             const float* __restrict__ s1, const float* __restrict__ s2,
             const float* __restrict__ mix, unsigned short* __restrict__ Acat, int M)
{
    const float m = mix[0], om = 1.0f - m;
    const int idx = blockIdx.x * 256 + threadIdx.x;       // over M*128 (4 cols each)
    const int row = idx >> 7;
    const int col = (idx & 127) * 4;
    if (row >= M) return;
    const size_t p = (size_t)row * 512 + col;
    const uint2 c1v = *(const uint2*)&c1[p];
    const uint2 c2v = *(const uint2*)&c2[p];
    const float4 s1v = *(const float4*)&s1[p];
    const float4 s2v = *(const float4*)&s2[p];
    uint2 o;
    float x0 = om * bflo(c1v.x) + m * bflo(c2v.x);
    float x1 = om * bfhi(c1v.x) + m * bfhi(c2v.x);
    float x2 = om * bflo(c1v.y) + m * bflo(c2v.y);
    float x3 = om * bfhi(c1v.y) + m * bfhi(c2v.y);
    o.x = (unsigned)f2bf(x0) | ((unsigned)f2bf(x1) << 16);
    o.y = (unsigned)f2bf(x2) | ((unsigned)f2bf(x3) << 16);
    *(uint2*)&Acat[(size_t)row * 1024 + col] = o;
    x0 = om * s1v.x + m * s2v.x;
    x1 = om * s1v.y + m * s2v.y;
    x2 = om * s1v.z + m * s2v.z;
    x3 = om * s1v.w + m * s2v.w;
    o.x = (unsigned)f2bf(x0) | ((unsigned)f2bf(x1) << 16);
    o.y = (unsigned)f2bf(x2) | ((unsigned)f2bf(x3) << 16);
    *(uint2*)&Acat[(size_t)row * 1024 + 512 + col] = o;
}

// ---------------------------------------------------------------------------
extern "C" void kernel_launch(void* const* d_in, const int* in_sizes, int n_in,
                              void* d_out, int out_size, void* d_ws, size_t ws_size,
                              hipStream_t stream) {
    const float* cs   = (const float*)d_in[0];
    const float* no   = (const float*)d_in[1];
    const float* Wq   = (const float*)d_in[2];
    const float* bq   = (const float*)d_in[3];
    const float* Wc   = (const float*)d_in[4];
    const float* v    = (const float*)d_in[5];
    const float* Wout = (const float*)d_in[6];
    const float* bout = (const float*)d_in[7];
    const float* mix  = (const float*)d_in[8];
    float* out = (float*)d_out;

    const int B = 32, L = 128, M = B * L;                 // 4096
    typedef unsigned short us;
    char* ws = (char*)d_ws;
    us* cs_bf  = (us*)(ws);                    // 4 MB
    us* no_bf  = (us*)(ws + (4u << 20));       // 4 MB
    us* Wqt    = (us*)(ws + (8u << 20));       // 0.5 MB  [512][512]
    us* Wct    = (us*)(ws + (8u << 20) + (512u << 10));
    us* Woutt  = (us*)(ws + (9u << 20));       // 1 MB    [512][1024]
    us* wq_bf  = (us*)(ws + (10u << 20));      // 4 MB
    us* uh_bf  = (us*)(ws + (14u << 20));      // 4 MB
    us* c1_bf  = (us*)(ws + (18u << 20));      // 4 MB
    us* c2_bf  = (us*)(ws + (22u << 20));      // 4 MB
    us* Acat   = (us*)(ws + (10u << 20));      // 8 MB, overlays wq/uh (dead)

    const dim3 b256(256);
    const int n8 = M * DD / 8;                             // 262144

    // prep: convert activations, transpose+convert weights
    f32_to_bf16_k<<<dim3(n8 / 256), b256, 0, stream>>>(cs, cs_bf, n8);
    f32_to_bf16_k<<<dim3(n8 / 256), b256, 0, stream>>>(no, no_bf, n8);
    transpose_bf16<<<dim3(8, 8),  b256, 0, stream>>>(Wq,   Wqt,   512, 512);
    transpose_bf16<<<dim3(8, 8),  b256, 0, stream>>>(Wc,   Wct,   512, 512);
    transpose_bf16<<<dim3(8, 16), b256, 0, stream>>>(Wout, Woutt, 1024, 512);

    const dim3 gg(DD / 64, M / 128);                       // (8, 32) = 256 blocks
    const dim3 ga(L / TT, B);                              // (8, 32)

    // direction 1: source=new_obs, memory=current_sotw
    gemm_mfma<512, true, true ><<<gg, b256, 0, stream>>>(no_bf, Wqt, bq,      (void*)wq_bf, DD);
    gemm_mfma<512, true, false><<<gg, b256, 0, stream>>>(cs_bf, Wct, nullptr, (void*)uh_bf, DD);
    attn_fused<<<ga, dim3(512), 0, stream>>>(wq_bf, uh_bf, v, cs, c1_bf);

    // direction 2: source=current_sotw, memory=new_obs
    gemm_mfma<512, true, true ><<<gg, b256, 0, stream>>>(cs_bf, Wqt, bq,      (void*)wq_bf, DD);
    gemm_mfma<512, true, false><<<gg, b256, 0, stream>>>(no_bf, Wct, nullptr, (void*)uh_bf, DD);
    attn_fused<<<ga, dim3(512), 0, stream>>>(wq_bf, uh_bf, v, no, c2_bf);

    // mix + concat (bf16), final GEMM K=1024 with bias -> f32 out
    mix_cat<<<dim3(M * 128 / 256), b256, 0, stream>>>(c1_bf, c2_bf, no, cs, mix, Acat, M);
    gemm_mfma<1024, false, false><<<gg, b256, 0, stream>>>(Acat, Woutt, bout, (void*)out, DD);
}